// Round 1
// baseline (99.230 us; speedup 1.0000x reference)
//
#include <hip/hip_runtime.h>

#define T_LEN 512

// Broadcast value from lane ((lane & 0x18) | k) within each 8-lane group
// (BitMode swizzle: offset = (xor<<10)|(or<<5)|and ; and=0x18 keeps group bits)
#define BCAST(v, k) __int_as_float(__builtin_amdgcn_ds_swizzle(__float_as_int(v), (((k) << 5) | 0x18)))
// xor-swizzle for butterfly reduce within 8-lane group
#define XSWZ(v, p) __int_as_float(__builtin_amdgcn_ds_swizzle(__float_as_int(v), (p)))

#define LOG2E 1.44269504f

// One GRU timestep for sub-iteration i (t = t0 + i), fully unrolled.
#define STEP(i)                                                                \
  do {                                                                         \
    const float xt = BCAST(xv, i);                                             \
    const float h0 = BCAST(h, 0), h1 = BCAST(h, 1);                            \
    const float h2 = BCAST(h, 2), h3 = BCAST(h, 3);                            \
    const float h4 = BCAST(h, 4), h5 = BCAST(h, 5);                            \
    const float h6 = BCAST(h, 6), h7 = BCAST(h, 7);                            \
    /* r-gate: two 4-deep FMA chains */                                        \
    float ar0 = __builtin_fmaf(wr0, h0, c_r);                                  \
    ar0 = __builtin_fmaf(wr1, h1, ar0);                                        \
    ar0 = __builtin_fmaf(wr2, h2, ar0);                                        \
    ar0 = __builtin_fmaf(wr3, h3, ar0);                                        \
    float ar1 = wr4 * h4;                                                      \
    ar1 = __builtin_fmaf(wr5, h5, ar1);                                        \
    ar1 = __builtin_fmaf(wr6, h6, ar1);                                        \
    ar1 = __builtin_fmaf(wr7, h7, ar1);                                        \
    /* z-gate */                                                               \
    float az0 = __builtin_fmaf(wz0, h0, c_z);                                  \
    az0 = __builtin_fmaf(wz1, h1, az0);                                        \
    az0 = __builtin_fmaf(wz2, h2, az0);                                        \
    az0 = __builtin_fmaf(wz3, h3, az0);                                        \
    float az1 = wz4 * h4;                                                      \
    az1 = __builtin_fmaf(wz5, h5, az1);                                        \
    az1 = __builtin_fmaf(wz6, h6, az1);                                        \
    az1 = __builtin_fmaf(wz7, h7, az1);                                        \
    /* n-gate hidden part (b_hh only; b_ih added on x side) */                 \
    float an0 = __builtin_fmaf(wn0, h0, c_n);                                  \
    an0 = __builtin_fmaf(wn1, h1, an0);                                        \
    an0 = __builtin_fmaf(wn2, h2, an0);                                        \
    an0 = __builtin_fmaf(wn3, h3, an0);                                        \
    float an1 = wn4 * h4;                                                      \
    an1 = __builtin_fmaf(wn5, h5, an1);                                        \
    an1 = __builtin_fmaf(wn6, h6, an1);                                        \
    an1 = __builtin_fmaf(wn7, h7, an1);                                        \
    const float sr = __builtin_fmaf(xt, wi_r, ar0 + ar1);                      \
    const float sz = __builtin_fmaf(xt, wi_z, az0 + az1);                      \
    const float r =                                                            \
        __builtin_amdgcn_rcpf(1.0f + __builtin_amdgcn_exp2f(sr * -LOG2E));    \
    const float z =                                                            \
        __builtin_amdgcn_rcpf(1.0f + __builtin_amdgcn_exp2f(sz * -LOG2E));    \
    const float xn = __builtin_fmaf(xt, wi_n, bi_n);                           \
    const float pn = __builtin_fmaf(r, an0 + an1, xn);                         \
    /* tanh(p) = 1 - 2/(exp2(2p*log2e)+1) */                                   \
    const float u =                                                            \
        __builtin_amdgcn_rcpf(1.0f + __builtin_amdgcn_exp2f(pn * (2.0f * LOG2E))); \
    const float n = __builtin_fmaf(-2.0f, u, 1.0f);                            \
    /* h' = (1-z)*n + z*h = n + z*(h-n) */                                     \
    h = __builtin_fmaf(z, h - n, n);                                           \
    /* y_t = sum_j h'_j * wfc_j + b_fc  (b_fc/8 folded per lane) */            \
    float m = __builtin_fmaf(h, wfc, bfc8);                                    \
    m += XSWZ(m, 0x041F);                                                      \
    m += XSWZ(m, 0x081F);                                                      \
    m += XSWZ(m, 0x101F);                                                      \
    ysel = is_##i ? m : ysel;                                                  \
  } while (0)

__global__ void __launch_bounds__(256) gru_fused(
    const float* __restrict__ x, const float* __restrict__ W_ih,
    const float* __restrict__ W_hh, const float* __restrict__ b_ih,
    const float* __restrict__ b_hh, const float* __restrict__ W_fc,
    const float* __restrict__ b_fc, float* __restrict__ out) {
  const int tid = blockIdx.x * blockDim.x + threadIdx.x;
  const int b = tid >> 3;  // batch index (8 lanes per batch)
  const int j = tid & 7;   // hidden-unit index within batch

  // Per-lane weights: gate rows j (r), 8+j (z), 16+j (n) of W_hh [24][8]
  const float* wr = W_hh + j * 8;
  const float* wz = W_hh + (8 + j) * 8;
  const float* wn = W_hh + (16 + j) * 8;
  const float wr0 = wr[0], wr1 = wr[1], wr2 = wr[2], wr3 = wr[3];
  const float wr4 = wr[4], wr5 = wr[5], wr6 = wr[6], wr7 = wr[7];
  const float wz0 = wz[0], wz1 = wz[1], wz2 = wz[2], wz3 = wz[3];
  const float wz4 = wz[4], wz5 = wz[5], wz6 = wz[6], wz7 = wz[7];
  const float wn0 = wn[0], wn1 = wn[1], wn2 = wn[2], wn3 = wn[3];
  const float wn4 = wn[4], wn5 = wn[5], wn6 = wn[6], wn7 = wn[7];

  const float c_r = b_ih[j] + b_hh[j];          // folded biases (r)
  const float c_z = b_ih[8 + j] + b_hh[8 + j];  // folded biases (z)
  const float c_n = b_hh[16 + j];               // n: hidden-side bias only
  const float bi_n = b_ih[16 + j];              // n: input-side bias
  const float wi_r = W_ih[j], wi_z = W_ih[8 + j], wi_n = W_ih[16 + j];
  const float wfc = W_fc[j];
  const float bfc8 = b_fc[0] * 0.125f;  // b_fc spread over 8 lanes

  // Hoisted lane-select masks (compiler keeps v_cmp results in SGPR pairs)
  const bool is_0 = (j == 0), is_1 = (j == 1), is_2 = (j == 2),
             is_3 = (j == 3);
  const bool is_4 = (j == 4), is_5 = (j == 5), is_6 = (j == 6),
             is_7 = (j == 7);

  const float* xp = x + (size_t)b * T_LEN;
  float* op = out + (size_t)b * T_LEN;

  float h = 0.0f;
  float xv = xp[j];  // lane j holds x[b][t0 + j] for the current 8-block
  for (int t0 = 0; t0 < T_LEN; t0 += 8) {
    float xv_next = 0.0f;
    if (t0 + 8 < T_LEN) xv_next = xp[t0 + 8 + j];  // prefetch next 8 steps
    float ysel = 0.0f;
    STEP(0);
    STEP(1);
    STEP(2);
    STEP(3);
    STEP(4);
    STEP(5);
    STEP(6);
    STEP(7);
    op[t0 + j] = ysel;  // lane j stores y[b][t0 + j] (coalesced per group)
    xv = xv_next;
  }
}

extern "C" void kernel_launch(void* const* d_in, const int* in_sizes, int n_in,
                              void* d_out, int out_size, void* d_ws,
                              size_t ws_size, hipStream_t stream) {
  const float* x = (const float*)d_in[0];
  const float* W_ih = (const float*)d_in[1];
  const float* W_hh = (const float*)d_in[2];
  const float* b_ih = (const float*)d_in[3];
  const float* b_hh = (const float*)d_in[4];
  const float* W_fc = (const float*)d_in[5];
  const float* b_fc = (const float*)d_in[6];
  float* out = (float*)d_out;

  const int B = in_sizes[0] / T_LEN;  // 8192
  const int threads = B * 8;          // 8 lanes per batch
  gru_fused<<<threads / 256, 256, 0, stream>>>(x, W_ih, W_hh, b_ih, b_hh, W_fc,
                                               b_fc, out);
}

// Round 2
// 62.096 us; speedup vs baseline: 1.5980x; 1.5980x over previous
//
#include <hip/hip_runtime.h>

#define T_LEN 512
#define LOG2E 1.44269504f

// DPP cross-lane (VALU pipe, ~4-8 cyc latency vs ~60 for ds_swizzle).
// Group-of-8 = quads {0,2} (or {1,3}) of a 16-lane DPP row, so unit-index
// xor maps to: xor1/xor2/xor3 -> quad_perm, xor4 -> row_ror:8 (lane xor8).
#define DPP_XOR1 0xB1   // quad_perm [1,0,3,2]
#define DPP_XOR2 0x4E   // quad_perm [2,3,0,1]
#define DPP_XOR3 0x1B   // quad_perm [3,2,1,0]
#define DPP_XOR8 0x128  // row_ror:8  (lane <- lane^8 within 16-row)

#define DPPF(v, ctrl)                                                      \
  __int_as_float(__builtin_amdgcn_update_dpp(0, __float_as_int(v), (ctrl), \
                                             0xF, 0xF, true))

// One GRU timestep. xi = x[b][t0+i] (register, uniform within group).
// Weights pre-scaled: r/z rows by -LOG2E, n rows by 2*LOG2E, so the
// exp2 args come straight out of the FMA chains (no per-step muls).
#define STEP(i, xi)                                                        \
  do {                                                                     \
    const float a0 = h;                                                    \
    const float a1 = DPPF(h, DPP_XOR1);  /* h[j^1] */                      \
    const float a2 = DPPF(h, DPP_XOR2);  /* h[j^2] */                      \
    const float a3 = DPPF(h, DPP_XOR3);  /* h[j^3] */                      \
    const float a4 = DPPF(a0, DPP_XOR8); /* h[j^4] */                      \
    const float a5 = DPPF(a1, DPP_XOR8); /* h[j^5] */                      \
    const float a6 = DPPF(a2, DPP_XOR8); /* h[j^6] */                      \
    const float a7 = DPPF(a3, DPP_XOR8); /* h[j^7] */                      \
    /* r-gate (pre-scaled by -LOG2E): two 4-deep chains */                 \
    float tr = __builtin_fmaf(xi, wi_r, c_r);                              \
    tr = __builtin_fmaf(wr0, a0, tr);                                      \
    tr = __builtin_fmaf(wr1, a1, tr);                                      \
    tr = __builtin_fmaf(wr2, a2, tr);                                      \
    tr = __builtin_fmaf(wr3, a3, tr);                                      \
    float ur = wr4 * a4;                                                   \
    ur = __builtin_fmaf(wr5, a5, ur);                                      \
    ur = __builtin_fmaf(wr6, a6, ur);                                      \
    ur = __builtin_fmaf(wr7, a7, ur);                                      \
    /* z-gate */                                                           \
    float tz = __builtin_fmaf(xi, wi_z, c_z);                              \
    tz = __builtin_fmaf(wz0, a0, tz);                                      \
    tz = __builtin_fmaf(wz1, a1, tz);                                      \
    tz = __builtin_fmaf(wz2, a2, tz);                                      \
    tz = __builtin_fmaf(wz3, a3, tz);                                      \
    float uz = wz4 * a4;                                                   \
    uz = __builtin_fmaf(wz5, a5, uz);                                      \
    uz = __builtin_fmaf(wz6, a6, uz);                                      \
    uz = __builtin_fmaf(wz7, a7, uz);                                      \
    /* n-gate hidden dot (pre-scaled by 2*LOG2E) */                        \
    float tn = __builtin_fmaf(wn0, a0, c_n);                               \
    tn = __builtin_fmaf(wn1, a1, tn);                                      \
    tn = __builtin_fmaf(wn2, a2, tn);                                      \
    tn = __builtin_fmaf(wn3, a3, tn);                                      \
    float un = wn4 * a4;                                                   \
    un = __builtin_fmaf(wn5, a5, un);                                      \
    un = __builtin_fmaf(wn6, a6, un);                                      \
    un = __builtin_fmaf(wn7, a7, un);                                      \
    const float r =                                                        \
        __builtin_amdgcn_rcpf(1.0f + __builtin_amdgcn_exp2f(tr + ur));     \
    const float z =                                                        \
        __builtin_amdgcn_rcpf(1.0f + __builtin_amdgcn_exp2f(tz + uz));     \
    const float xn = __builtin_fmaf(xi, wi_n, bi_n);                       \
    const float pn = __builtin_fmaf(r, tn + un, xn);                       \
    const float uu =                                                       \
        __builtin_amdgcn_rcpf(1.0f + __builtin_amdgcn_exp2f(pn));          \
    const float nn = __builtin_fmaf(-2.0f, uu, 1.0f); /* tanh */           \
    h = __builtin_fmaf(z, a0 - nn, nn); /* h' = n + z*(h-n) */             \
    /* y_t = sum_j h'_j * wfc_j + b_fc : DPP butterfly over the group */   \
    float m = __builtin_fmaf(h, wfc, bfc8);                                \
    m += DPPF(m, DPP_XOR1);                                                \
    m += DPPF(m, DPP_XOR2);                                                \
    m += DPPF(m, DPP_XOR8);                                                \
    ysel = is_##i ? m : ysel;                                              \
  } while (0)

__global__ void __launch_bounds__(256) gru_fused(
    const float* __restrict__ x, const float* __restrict__ W_ih,
    const float* __restrict__ W_hh, const float* __restrict__ b_ih,
    const float* __restrict__ b_hh, const float* __restrict__ W_fc,
    const float* __restrict__ b_fc, float* __restrict__ out) {
  const int tid = blockIdx.x * blockDim.x + threadIdx.x;
  // 8-lane group = quads {0,2} or {1,3} of a 16-lane row.
  const int pos = tid & 3;          // position within quad
  const int grp = (tid >> 2) & 1;   // which batch of the row-pair
  const int hlf = (tid >> 3) & 1;   // which quad-pair half
  const int j = pos | (hlf << 2);   // hidden unit owned by this lane
  const int b = ((tid >> 4) << 1) | grp;  // batch index

  // Per-lane weight rows j (r), 8+j (z), 16+j (n); columns XOR-permuted to
  // match the DPP gather order (a_m = h[j^m]).
  const float* wr = W_hh + j * 8;
  const float* wz = W_hh + (8 + j) * 8;
  const float* wn = W_hh + (16 + j) * 8;
  const float SN = -LOG2E, SP = 2.0f * LOG2E;
  const float wr0 = SN * wr[j ^ 0], wr1 = SN * wr[j ^ 1];
  const float wr2 = SN * wr[j ^ 2], wr3 = SN * wr[j ^ 3];
  const float wr4 = SN * wr[j ^ 4], wr5 = SN * wr[j ^ 5];
  const float wr6 = SN * wr[j ^ 6], wr7 = SN * wr[j ^ 7];
  const float wz0 = SN * wz[j ^ 0], wz1 = SN * wz[j ^ 1];
  const float wz2 = SN * wz[j ^ 2], wz3 = SN * wz[j ^ 3];
  const float wz4 = SN * wz[j ^ 4], wz5 = SN * wz[j ^ 5];
  const float wz6 = SN * wz[j ^ 6], wz7 = SN * wz[j ^ 7];
  const float wn0 = SP * wn[j ^ 0], wn1 = SP * wn[j ^ 1];
  const float wn2 = SP * wn[j ^ 2], wn3 = SP * wn[j ^ 3];
  const float wn4 = SP * wn[j ^ 4], wn5 = SP * wn[j ^ 5];
  const float wn6 = SP * wn[j ^ 6], wn7 = SP * wn[j ^ 7];

  const float c_r = SN * (b_ih[j] + b_hh[j]);
  const float c_z = SN * (b_ih[8 + j] + b_hh[8 + j]);
  const float c_n = SP * b_hh[16 + j];
  const float bi_n = SP * b_ih[16 + j];
  const float wi_r = SN * W_ih[j], wi_z = SN * W_ih[8 + j],
              wi_n = SP * W_ih[16 + j];
  const float wfc = W_fc[j];
  const float bfc8 = b_fc[0] * 0.125f;

  const bool is_0 = (j == 0), is_1 = (j == 1), is_2 = (j == 2),
             is_3 = (j == 3);
  const bool is_4 = (j == 4), is_5 = (j == 5), is_6 = (j == 6),
             is_7 = (j == 7);

  const float* xp = x + (size_t)b * T_LEN;
  float* op = out + (size_t)b * T_LEN;

  float h = 0.0f;
  // Every lane of the group loads the group's 8 x values (same address
  // across lanes -> single 32B segment, HW-broadcast). No per-step bcast.
  const float4* xq = reinterpret_cast<const float4*>(xp);
  float4 cA = xq[0], cB = xq[1];
  for (int t0 = 0; t0 < T_LEN; t0 += 8) {
    float4 nA, nB;
    if (t0 + 8 < T_LEN) {  // prefetch next 8 steps
      nA = xq[(t0 >> 2) + 2];
      nB = xq[(t0 >> 2) + 3];
    } else {
      nA = cA;
      nB = cB;
    }
    float ysel = 0.0f;
    STEP(0, cA.x);
    STEP(1, cA.y);
    STEP(2, cA.z);
    STEP(3, cA.w);
    STEP(4, cB.x);
    STEP(5, cB.y);
    STEP(6, cB.z);
    STEP(7, cB.w);
    op[t0 + j] = ysel;
    cA = nA;
    cB = nB;
  }
}

extern "C" void kernel_launch(void* const* d_in, const int* in_sizes, int n_in,
                              void* d_out, int out_size, void* d_ws,
                              size_t ws_size, hipStream_t stream) {
  const float* x = (const float*)d_in[0];
  const float* W_ih = (const float*)d_in[1];
  const float* W_hh = (const float*)d_in[2];
  const float* b_ih = (const float*)d_in[3];
  const float* b_hh = (const float*)d_in[4];
  const float* W_fc = (const float*)d_in[5];
  const float* b_fc = (const float*)d_in[6];
  float* out = (float*)d_out;

  const int B = in_sizes[0] / T_LEN;  // 8192
  const int threads = B * 8;          // 8 lanes per batch
  gru_fused<<<threads / 256, 256, 0, stream>>>(x, W_ih, W_hh, b_ih, b_hh, W_fc,
                                               b_fc, out);
}

// Round 4
// 59.843 us; speedup vs baseline: 1.6582x; 1.0377x over previous
//
#include <hip/hip_runtime.h>

// Must match the element type of __builtin_amdgcn_cvt_pkrtz's return value
// (__fp16, not _Float16 -- clang treats them as distinct vector types).
typedef __fp16 f16x2 __attribute__((ext_vector_type(2)));

#define T_LEN 512
#define LOG2E 1.44269504f

// DPP cross-lane (VALU pipe). 8-lane group = quads {0,2} (or {1,3}) of a
// 16-lane DPP row: unit-index xor1/2/3 -> quad_perm, xor4 -> row_ror:8.
#define DPP_XOR1 0xB1   // quad_perm [1,0,3,2]
#define DPP_XOR2 0x4E   // quad_perm [2,3,0,1]
#define DPP_XOR3 0x1B   // quad_perm [3,2,1,0]
#define DPP_XOR8 0x128  // row_ror:8 (lane <- lane^8 within 16-row)

#define DPPI(v, ctrl) __builtin_amdgcn_update_dpp(0, (v), (ctrl), 0xF, 0xF, true)
#define DPPF(v, ctrl) __int_as_float(DPPI(__float_as_int(v), (ctrl)))
#define DPPH2(v, ctrl) \
  __builtin_bit_cast(f16x2, DPPI(__builtin_bit_cast(int, (v)), (ctrl)))

#define FDOT2(a, b, c) __builtin_amdgcn_fdot2((a), (b), (c), false)

// One GRU timestep. Hidden dots in packed f16 (f32 accumulate); recurrence,
// activations, and y-reduce stay f32. Weights pre-scaled so exp2 args come
// straight out of the dot chains (r/z by -LOG2E, n by 2*LOG2E).
#define STEP(i, xi)                                                         \
  do {                                                                      \
    /* pack h[j^0..7] as 4 f16x2 regs: 1 cvt + 1 dpp + 3 packed dpp */      \
    const f16x2 p01 = __builtin_amdgcn_cvt_pkrtz(h, DPPF(h, DPP_XOR1));     \
    const f16x2 p45 = DPPH2(p01, DPP_XOR8); /* (h[j^4],h[j^5]) */           \
    const f16x2 p23 = DPPH2(p01, DPP_XOR2); /* (h[j^2],h[j^3]) */           \
    const f16x2 p67 = DPPH2(p45, DPP_XOR2); /* (h[j^6],h[j^7]) */           \
    /* r-gate: two 2-deep fdot2 chains */                                   \
    float rA = FDOT2(p01, wr0, __builtin_fmaf(xi, wi_r, c_r));              \
    rA = FDOT2(p23, wr1, rA);                                               \
    float rB = FDOT2(p45, wr2, 0.0f);                                       \
    rB = FDOT2(p67, wr3, rB);                                               \
    /* z-gate */                                                            \
    float zA = FDOT2(p01, wz0, __builtin_fmaf(xi, wi_z, c_z));              \
    zA = FDOT2(p23, wz1, zA);                                               \
    float zB = FDOT2(p45, wz2, 0.0f);                                       \
    zB = FDOT2(p67, wz3, zB);                                               \
    /* n-gate hidden dot */                                                 \
    float nA = FDOT2(p01, wn0, c_n);                                        \
    nA = FDOT2(p23, wn1, nA);                                               \
    float nB = FDOT2(p45, wn2, 0.0f);                                       \
    nB = FDOT2(p67, wn3, nB);                                               \
    const float r =                                                         \
        __builtin_amdgcn_rcpf(1.0f + __builtin_amdgcn_exp2f(rA + rB));      \
    const float z =                                                         \
        __builtin_amdgcn_rcpf(1.0f + __builtin_amdgcn_exp2f(zA + zB));      \
    const float omz = 1.0f - z;    /* overlaps tanh latency */              \
    const float zh = z * h;        /* overlaps tanh latency */              \
    const float xn = __builtin_fmaf(xi, wi_n, bi_n);                        \
    const float pn = __builtin_fmaf(r, nA + nB, xn);                        \
    const float uu =                                                        \
        __builtin_amdgcn_rcpf(1.0f + __builtin_amdgcn_exp2f(pn));           \
    const float nn = __builtin_fmaf(-2.0f, uu, 1.0f); /* tanh */            \
    h = __builtin_fmaf(omz, nn, zh); /* h' = (1-z)*n + z*h */               \
    /* y_t: f32 DPP butterfly over the 8-lane group */                      \
    float m = __builtin_fmaf(h, wfc, bfc8);                                 \
    m += DPPF(m, DPP_XOR1);                                                 \
    m += DPPF(m, DPP_XOR2);                                                 \
    m += DPPF(m, DPP_XOR8);                                                 \
    ysel = is_##i ? m : ysel;                                               \
  } while (0)

__global__ void __launch_bounds__(256) gru_fused(
    const float* __restrict__ x, const float* __restrict__ W_ih,
    const float* __restrict__ W_hh, const float* __restrict__ b_ih,
    const float* __restrict__ b_hh, const float* __restrict__ W_fc,
    const float* __restrict__ b_fc, float* __restrict__ out) {
  const int tid = blockIdx.x * blockDim.x + threadIdx.x;
  // 8-lane group = quads {0,2} or {1,3} of a 16-lane row.
  const int pos = tid & 3;
  const int grp = (tid >> 2) & 1;
  const int hlf = (tid >> 3) & 1;
  const int j = pos | (hlf << 2);          // hidden unit owned by this lane
  const int b = ((tid >> 4) << 1) | grp;   // batch index

  const float* wr = W_hh + j * 8;
  const float* wz = W_hh + (8 + j) * 8;
  const float* wn = W_hh + (16 + j) * 8;
  const float SN = -LOG2E, SP = 2.0f * LOG2E;
  // Packed f16 weight pairs, column-permuted to match (h[j^2m], h[j^2m+1]).
  const f16x2 wr0 = __builtin_amdgcn_cvt_pkrtz(SN * wr[j ^ 0], SN * wr[j ^ 1]);
  const f16x2 wr1 = __builtin_amdgcn_cvt_pkrtz(SN * wr[j ^ 2], SN * wr[j ^ 3]);
  const f16x2 wr2 = __builtin_amdgcn_cvt_pkrtz(SN * wr[j ^ 4], SN * wr[j ^ 5]);
  const f16x2 wr3 = __builtin_amdgcn_cvt_pkrtz(SN * wr[j ^ 6], SN * wr[j ^ 7]);
  const f16x2 wz0 = __builtin_amdgcn_cvt_pkrtz(SN * wz[j ^ 0], SN * wz[j ^ 1]);
  const f16x2 wz1 = __builtin_amdgcn_cvt_pkrtz(SN * wz[j ^ 2], SN * wz[j ^ 3]);
  const f16x2 wz2 = __builtin_amdgcn_cvt_pkrtz(SN * wz[j ^ 4], SN * wz[j ^ 5]);
  const f16x2 wz3 = __builtin_amdgcn_cvt_pkrtz(SN * wz[j ^ 6], SN * wz[j ^ 7]);
  const f16x2 wn0 = __builtin_amdgcn_cvt_pkrtz(SP * wn[j ^ 0], SP * wn[j ^ 1]);
  const f16x2 wn1 = __builtin_amdgcn_cvt_pkrtz(SP * wn[j ^ 2], SP * wn[j ^ 3]);
  const f16x2 wn2 = __builtin_amdgcn_cvt_pkrtz(SP * wn[j ^ 4], SP * wn[j ^ 5]);
  const f16x2 wn3 = __builtin_amdgcn_cvt_pkrtz(SP * wn[j ^ 6], SP * wn[j ^ 7]);

  const float c_r = SN * (b_ih[j] + b_hh[j]);
  const float c_z = SN * (b_ih[8 + j] + b_hh[8 + j]);
  const float c_n = SP * b_hh[16 + j];
  const float bi_n = SP * b_ih[16 + j];
  const float wi_r = SN * W_ih[j], wi_z = SN * W_ih[8 + j],
              wi_n = SP * W_ih[16 + j];
  const float wfc = W_fc[j];
  const float bfc8 = b_fc[0] * 0.125f;

  const bool is_0 = (j == 0), is_1 = (j == 1), is_2 = (j == 2),
             is_3 = (j == 3);
  const bool is_4 = (j == 4), is_5 = (j == 5), is_6 = (j == 6),
             is_7 = (j == 7);

  const float* xp = x + (size_t)b * T_LEN;
  float* op = out + (size_t)b * T_LEN;

  float h = 0.0f;
  // All 8 lanes of the group load the group's 8 x values (same address
  // across lanes -> HW broadcast); step i reads a register component.
  const float4* xq = reinterpret_cast<const float4*>(xp);
  float4 cA = xq[0], cB = xq[1];
  for (int t0 = 0; t0 < T_LEN; t0 += 8) {
    float4 nA4, nB4;
    if (t0 + 8 < T_LEN) {  // prefetch next 8 steps
      nA4 = xq[(t0 >> 2) + 2];
      nB4 = xq[(t0 >> 2) + 3];
    } else {
      nA4 = cA;
      nB4 = cB;
    }
    float ysel = 0.0f;
    STEP(0, cA.x);
    STEP(1, cA.y);
    STEP(2, cA.z);
    STEP(3, cA.w);
    STEP(4, cB.x);
    STEP(5, cB.y);
    STEP(6, cB.z);
    STEP(7, cB.w);
    op[t0 + j] = ysel;
    cA = nA4;
    cB = nB4;
  }
}

extern "C" void kernel_launch(void* const* d_in, const int* in_sizes, int n_in,
                              void* d_out, int out_size, void* d_ws,
                              size_t ws_size, hipStream_t stream) {
  const float* x = (const float*)d_in[0];
  const float* W_ih = (const float*)d_in[1];
  const float* W_hh = (const float*)d_in[2];
  const float* b_ih = (const float*)d_in[3];
  const float* b_hh = (const float*)d_in[4];
  const float* W_fc = (const float*)d_in[5];
  const float* b_fc = (const float*)d_in[6];
  float* out = (float*)d_out;

  const int B = in_sizes[0] / T_LEN;  // 8192
  const int threads = B * 8;          // 8 lanes per batch
  gru_fused<<<threads / 256, 256, 0, stream>>>(x, W_ih, W_hh, b_ih, b_hh, W_fc,
                                               b_fc, out);
}

// Round 5
// 57.142 us; speedup vs baseline: 1.7365x; 1.0473x over previous
//
#include <hip/hip_runtime.h>

// Must match the element type of __builtin_amdgcn_cvt_pkrtz's return value.
typedef __fp16 f16x2 __attribute__((ext_vector_type(2)));

#define T_LEN 512
#define LOG2E 1.44269504f

// DPP cross-lane (VALU pipe). 8-lane group = quads {0,2} (or {1,3}) of a
// 16-lane DPP row: unit-index xor1/2/3 -> quad_perm, xor4 -> row_ror:8.
#define DPP_XOR1 0xB1   // quad_perm [1,0,3,2]
#define DPP_XOR2 0x4E   // quad_perm [2,3,0,1]
#define DPP_XOR8 0x128  // row_ror:8 (lane <- lane^8 within 16-row)

#define DPPI(v, ctrl) __builtin_amdgcn_update_dpp(0, (v), (ctrl), 0xF, 0xF, true)
#define DPPF(v, ctrl) __int_as_float(DPPI(__float_as_int(v), (ctrl)))
#define DPPH2(v, ctrl) \
  __builtin_bit_cast(f16x2, DPPI(__builtin_bit_cast(int, (v)), (ctrl)))

#define FDOT2(a, b, c) __builtin_amdgcn_fdot2((a), (b), (c), false)

// One GRU timestep. Hidden dots packed f16 (f32 accumulate); shared rcp for
// the two sigmoids (exact); per-step y work is a single fma into mdst.
#define STEP(xi, mdst)                                                      \
  do {                                                                      \
    const f16x2 p01 = __builtin_amdgcn_cvt_pkrtz(h, DPPF(h, DPP_XOR1));     \
    const f16x2 p45 = DPPH2(p01, DPP_XOR8); /* (h[j^4],h[j^5]) */           \
    const f16x2 p23 = DPPH2(p01, DPP_XOR2); /* (h[j^2],h[j^3]) */           \
    const f16x2 p67 = DPPH2(p45, DPP_XOR2); /* (h[j^6],h[j^7]) */           \
    float rA = FDOT2(p01, wr0, __builtin_fmaf(xi, wi_r, c_r));              \
    rA = FDOT2(p23, wr1, rA);                                               \
    float rB = FDOT2(p45, wr2, 0.0f);                                       \
    rB = FDOT2(p67, wr3, rB);                                               \
    float zA = FDOT2(p01, wz0, __builtin_fmaf(xi, wi_z, c_z));              \
    zA = FDOT2(p23, wz1, zA);                                               \
    float zB = FDOT2(p45, wz2, 0.0f);                                       \
    zB = FDOT2(p67, wz3, zB);                                               \
    float nA = FDOT2(p01, wn0, c_n);                                        \
    nA = FDOT2(p23, wn1, nA);                                               \
    float nB = FDOT2(p45, wn2, 0.0f);                                       \
    nB = FDOT2(p67, wn3, nB);                                               \
    const float er = __builtin_amdgcn_exp2f(rA + rB);                       \
    const float ez = __builtin_amdgcn_exp2f(zA + zB);                       \
    const float dr = 1.0f + er, dz = 1.0f + ez;                             \
    const float q = __builtin_amdgcn_rcpf(dr * dz); /* shared rcp */        \
    const float r = dz * q; /* = 1/dr = sigmoid(sr) */                      \
    const float z = dr * q; /* = 1/dz = sigmoid(sz) */                      \
    const float omz = 1.0f - z;                                             \
    const float zh = z * h;                                                 \
    const float xn = __builtin_fmaf(xi, wi_n, bi_n);                        \
    const float pn = __builtin_fmaf(r, nA + nB, xn);                        \
    const float uu =                                                        \
        __builtin_amdgcn_rcpf(1.0f + __builtin_amdgcn_exp2f(pn));           \
    const float nn = __builtin_fmaf(-2.0f, uu, 1.0f); /* tanh */            \
    h = __builtin_fmaf(omz, nn, zh); /* h' = (1-z)*n + z*h */               \
    mdst = __builtin_fmaf(h, wfc, bfc8);                                    \
  } while (0)

// Transpose-reduce 8 per-step partials: y[t0+k] = sum over the 8 group
// lanes of m_k, delivered at lane j==k. 14 DPP + 14 add + 7 cndmask,
// all chain-independent (fills exp2/rcp stall slots of adjacent steps).
#define BFLY_STORE(m0, m1, m2, m3, m4, m5, m6, m7, dst)                     \
  do {                                                                      \
    float s0 = m0 + DPPF(m0, DPP_XOR1);                                     \
    float s1 = m1 + DPPF(m1, DPP_XOR1);                                     \
    float s2 = m2 + DPPF(m2, DPP_XOR1);                                     \
    float s3 = m3 + DPPF(m3, DPP_XOR1);                                     \
    float s4 = m4 + DPPF(m4, DPP_XOR1);                                     \
    float s5 = m5 + DPPF(m5, DPP_XOR1);                                     \
    float s6 = m6 + DPPF(m6, DPP_XOR1);                                     \
    float s7 = m7 + DPPF(m7, DPP_XOR1);                                     \
    float t0_ = sel1 ? s1 : s0;                                             \
    float t1_ = sel1 ? s3 : s2;                                             \
    float t2_ = sel1 ? s5 : s4;                                             \
    float t3_ = sel1 ? s7 : s6;                                             \
    t0_ += DPPF(t0_, DPP_XOR2);                                             \
    t1_ += DPPF(t1_, DPP_XOR2);                                             \
    t2_ += DPPF(t2_, DPP_XOR2);                                             \
    t3_ += DPPF(t3_, DPP_XOR2);                                             \
    float u0_ = sel2 ? t1_ : t0_;                                           \
    float u1_ = sel2 ? t3_ : t2_;                                           \
    u0_ += DPPF(u0_, DPP_XOR8);                                             \
    u1_ += DPPF(u1_, DPP_XOR8);                                             \
    (dst) = sel4 ? u1_ : u0_;                                               \
  } while (0)

__global__ void __launch_bounds__(256) gru_fused(
    const float* __restrict__ x, const float* __restrict__ W_ih,
    const float* __restrict__ W_hh, const float* __restrict__ b_ih,
    const float* __restrict__ b_hh, const float* __restrict__ W_fc,
    const float* __restrict__ b_fc, float* __restrict__ out) {
  const int tid = blockIdx.x * blockDim.x + threadIdx.x;
  // 8-lane group = quads {0,2} or {1,3} of a 16-lane row.
  const int pos = tid & 3;
  const int grp = (tid >> 2) & 1;
  const int hlf = (tid >> 3) & 1;
  const int j = pos | (hlf << 2);          // hidden unit owned by this lane
  const int b = ((tid >> 4) << 1) | grp;   // batch index

  const float* wr = W_hh + j * 8;
  const float* wz = W_hh + (8 + j) * 8;
  const float* wn = W_hh + (16 + j) * 8;
  const float SN = -LOG2E, SP = 2.0f * LOG2E;
  // Packed f16 weight pairs, column-permuted to match (h[j^2m], h[j^2m+1]).
  const f16x2 wr0 = __builtin_amdgcn_cvt_pkrtz(SN * wr[j ^ 0], SN * wr[j ^ 1]);
  const f16x2 wr1 = __builtin_amdgcn_cvt_pkrtz(SN * wr[j ^ 2], SN * wr[j ^ 3]);
  const f16x2 wr2 = __builtin_amdgcn_cvt_pkrtz(SN * wr[j ^ 4], SN * wr[j ^ 5]);
  const f16x2 wr3 = __builtin_amdgcn_cvt_pkrtz(SN * wr[j ^ 6], SN * wr[j ^ 7]);
  const f16x2 wz0 = __builtin_amdgcn_cvt_pkrtz(SN * wz[j ^ 0], SN * wz[j ^ 1]);
  const f16x2 wz1 = __builtin_amdgcn_cvt_pkrtz(SN * wz[j ^ 2], SN * wz[j ^ 3]);
  const f16x2 wz2 = __builtin_amdgcn_cvt_pkrtz(SN * wz[j ^ 4], SN * wz[j ^ 5]);
  const f16x2 wz3 = __builtin_amdgcn_cvt_pkrtz(SN * wz[j ^ 6], SN * wz[j ^ 7]);
  const f16x2 wn0 = __builtin_amdgcn_cvt_pkrtz(SP * wn[j ^ 0], SP * wn[j ^ 1]);
  const f16x2 wn1 = __builtin_amdgcn_cvt_pkrtz(SP * wn[j ^ 2], SP * wn[j ^ 3]);
  const f16x2 wn2 = __builtin_amdgcn_cvt_pkrtz(SP * wn[j ^ 4], SP * wn[j ^ 5]);
  const f16x2 wn3 = __builtin_amdgcn_cvt_pkrtz(SP * wn[j ^ 6], SP * wn[j ^ 7]);

  const float c_r = SN * (b_ih[j] + b_hh[j]);
  const float c_z = SN * (b_ih[8 + j] + b_hh[8 + j]);
  const float c_n = SP * b_hh[16 + j];
  const float bi_n = SP * b_ih[16 + j];
  const float wi_r = SN * W_ih[j], wi_z = SN * W_ih[8 + j],
              wi_n = SP * W_ih[16 + j];
  const float wfc = W_fc[j];
  const float bfc8 = b_fc[0] * 0.125f;

  // Hoisted butterfly lane-select masks (v_cmp results live in SGPR pairs).
  const bool sel1 = (j & 1) != 0;
  const bool sel2 = (j & 2) != 0;
  const bool sel4 = (j & 4) != 0;

  const float* xp = x + (size_t)b * T_LEN;
  float* op = out + (size_t)b * T_LEN;

  float h = 0.0f;
  // All 8 lanes of the group load the group's 16 x values (same address
  // across lanes -> HW broadcast); step i reads a register component.
  const float4* xq = reinterpret_cast<const float4*>(xp);
  float4 cA = xq[0], cB = xq[1], cC = xq[2], cD = xq[3];
  for (int t0 = 0; t0 < T_LEN; t0 += 16) {
    float4 nA4 = cA, nB4 = cB, nC4 = cC, nD4 = cD;
    if (t0 + 16 < T_LEN) {  // prefetch next 16 steps
      nA4 = xq[(t0 >> 2) + 4];
      nB4 = xq[(t0 >> 2) + 5];
      nC4 = xq[(t0 >> 2) + 6];
      nD4 = xq[(t0 >> 2) + 7];
    }
    float mA0, mA1, mA2, mA3, mA4, mA5, mA6, mA7;
    float mB0, mB1, mB2, mB3, mB4, mB5, mB6, mB7;
    STEP(cA.x, mA0);
    STEP(cA.y, mA1);
    STEP(cA.z, mA2);
    STEP(cA.w, mA3);
    STEP(cB.x, mA4);
    STEP(cB.y, mA5);
    STEP(cB.z, mA6);
    STEP(cB.w, mA7);
    // Butterfly A interleaves with steps 8-15 below (same basic block).
    BFLY_STORE(mA0, mA1, mA2, mA3, mA4, mA5, mA6, mA7, op[t0 + j]);
    STEP(cC.x, mB0);
    STEP(cC.y, mB1);
    STEP(cC.z, mB2);
    STEP(cC.w, mB3);
    STEP(cD.x, mB4);
    STEP(cD.y, mB5);
    STEP(cD.z, mB6);
    STEP(cD.w, mB7);
    BFLY_STORE(mB0, mB1, mB2, mB3, mB4, mB5, mB6, mB7, op[t0 + 8 + j]);
    cA = nA4;
    cB = nB4;
    cC = nC4;
    cD = nD4;
  }
}

extern "C" void kernel_launch(void* const* d_in, const int* in_sizes, int n_in,
                              void* d_out, int out_size, void* d_ws,
                              size_t ws_size, hipStream_t stream) {
  const float* x = (const float*)d_in[0];
  const float* W_ih = (const float*)d_in[1];
  const float* W_hh = (const float*)d_in[2];
  const float* b_ih = (const float*)d_in[3];
  const float* b_hh = (const float*)d_in[4];
  const float* W_fc = (const float*)d_in[5];
  const float* b_fc = (const float*)d_in[6];
  float* out = (float*)d_out;

  const int B = in_sizes[0] / T_LEN;  // 8192
  const int threads = B * 8;          // 8 lanes per batch
  gru_fused<<<threads / 256, 256, 0, stream>>>(x, W_ih, W_hh, b_ih, b_hh, W_fc,
                                               b_fc, out);
}

// Round 6
// 54.730 us; speedup vs baseline: 1.8131x; 1.0441x over previous
//
#include <hip/hip_runtime.h>

// Must match the element type of __builtin_amdgcn_cvt_pkrtz's return value.
typedef __fp16 f16x2 __attribute__((ext_vector_type(2)));

#define T_LEN 512
#define LOG2E 1.44269504f

// DPP cross-lane (VALU pipe). 8-lane group = quads {0,2} (or {1,3}) of a
// 16-lane DPP row: unit-index xor1/2/3 -> quad_perm, xor4 -> row_ror:8.
#define DPP_XOR1 0xB1   // quad_perm [1,0,3,2]
#define DPP_XOR2 0x4E   // quad_perm [2,3,0,1]
#define DPP_XOR8 0x128  // row_ror:8 (lane <- lane^8 within 16-row)

#define DPPI(v, ctrl) __builtin_amdgcn_update_dpp(0, (v), (ctrl), 0xF, 0xF, true)
#define DPPF(v, ctrl) __int_as_float(DPPI(__float_as_int(v), (ctrl)))
#define DPPH2(v, ctrl) \
  __builtin_bit_cast(f16x2, DPPI(__builtin_bit_cast(int, (v)), (ctrl)))

#define FDOT2(a, b, c) __builtin_amdgcn_fdot2((a), (b), (c), false)

// One GRU timestep, chain-minimized form (exact algebra):
//   r  = 1/(1+er)                      er = exp2(-sr*log2e)
//   h' = [(ez+h)*ep + (h-ez)] / [dz*(1+ep)]
// where ez = exp2(-sz*log2e), dz = 1+ez, ep = exp2(2*pn*log2e).
// This folds z-blend and tanh's divide into ONE rcp, and r's rcp takes dr
// directly (no shared-product muls on the chain).
#define STEP(xi, mdst)                                                      \
  do {                                                                      \
    const f16x2 p01 = __builtin_amdgcn_cvt_pkrtz(h, DPPF(h, DPP_XOR1));     \
    const f16x2 p45 = DPPH2(p01, DPP_XOR8); /* (h[j^4],h[j^5]) */           \
    const f16x2 p23 = DPPH2(p01, DPP_XOR2); /* (h[j^2],h[j^3]) */           \
    const f16x2 p67 = DPPH2(p45, DPP_XOR2); /* (h[j^6],h[j^7]) */           \
    float rA = FDOT2(p01, wr0, __builtin_fmaf(xi, wi_r, c_r));              \
    rA = FDOT2(p23, wr1, rA);                                               \
    float rB = FDOT2(p45, wr2, 0.0f);                                       \
    rB = FDOT2(p67, wr3, rB);                                               \
    float zA = FDOT2(p01, wz0, __builtin_fmaf(xi, wi_z, c_z));              \
    zA = FDOT2(p23, wz1, zA);                                               \
    float zB = FDOT2(p45, wz2, 0.0f);                                       \
    zB = FDOT2(p67, wz3, zB);                                               \
    float nA = FDOT2(p01, wn0, c_n);                                        \
    nA = FDOT2(p23, wn1, nA);                                               \
    float nB = FDOT2(p45, wn2, 0.0f);                                       \
    nB = FDOT2(p67, wn3, nB);                                               \
    const float er = __builtin_amdgcn_exp2f(rA + rB);                       \
    const float ez = __builtin_amdgcn_exp2f(zA + zB);                       \
    const float r = __builtin_amdgcn_rcpf(1.0f + er); /* sigmoid(sr) */     \
    const float dz = 1.0f + ez;                                             \
    const float ezh = ez + h;  /* off-chain vs rcp/exp2 */                  \
    const float hez = h - ez;  /* off-chain */                              \
    const float xn = __builtin_fmaf(xi, wi_n, bi_n);                        \
    const float pn = __builtin_fmaf(r, nA + nB, xn);                        \
    const float ep = __builtin_amdgcn_exp2f(pn);                            \
    const float dp = 1.0f + ep;                                             \
    const float den = dz * dp;                                              \
    const float num = __builtin_fmaf(ezh, ep, hez); /* || with den */       \
    h = num * __builtin_amdgcn_rcpf(den);                                   \
    mdst = __builtin_fmaf(h, wfc, bfc8);                                    \
  } while (0)

// Transpose-reduce 8 per-step partials: y[t0+k] = sum over the 8 group
// lanes of m_k, delivered at lane j==k.
#define BFLY_STORE(m0, m1, m2, m3, m4, m5, m6, m7, dst)                     \
  do {                                                                      \
    float s0 = m0 + DPPF(m0, DPP_XOR1);                                     \
    float s1 = m1 + DPPF(m1, DPP_XOR1);                                     \
    float s2 = m2 + DPPF(m2, DPP_XOR1);                                     \
    float s3 = m3 + DPPF(m3, DPP_XOR1);                                     \
    float s4 = m4 + DPPF(m4, DPP_XOR1);                                     \
    float s5 = m5 + DPPF(m5, DPP_XOR1);                                     \
    float s6 = m6 + DPPF(m6, DPP_XOR1);                                     \
    float s7 = m7 + DPPF(m7, DPP_XOR1);                                     \
    float t0_ = sel1 ? s1 : s0;                                             \
    float t1_ = sel1 ? s3 : s2;                                             \
    float t2_ = sel1 ? s5 : s4;                                             \
    float t3_ = sel1 ? s7 : s6;                                             \
    t0_ += DPPF(t0_, DPP_XOR2);                                             \
    t1_ += DPPF(t1_, DPP_XOR2);                                             \
    t2_ += DPPF(t2_, DPP_XOR2);                                             \
    t3_ += DPPF(t3_, DPP_XOR2);                                             \
    float u0_ = sel2 ? t1_ : t0_;                                           \
    float u1_ = sel2 ? t3_ : t2_;                                           \
    u0_ += DPPF(u0_, DPP_XOR8);                                             \
    u1_ += DPPF(u1_, DPP_XOR8);                                             \
    (dst) = sel4 ? u1_ : u0_;                                               \
  } while (0)

__global__ void __launch_bounds__(256) gru_fused(
    const float* __restrict__ x, const float* __restrict__ W_ih,
    const float* __restrict__ W_hh, const float* __restrict__ b_ih,
    const float* __restrict__ b_hh, const float* __restrict__ W_fc,
    const float* __restrict__ b_fc, float* __restrict__ out) {
  const int tid = blockIdx.x * blockDim.x + threadIdx.x;
  // 8-lane group = quads {0,2} or {1,3} of a 16-lane row.
  const int pos = tid & 3;
  const int grp = (tid >> 2) & 1;
  const int hlf = (tid >> 3) & 1;
  const int j = pos | (hlf << 2);          // hidden unit owned by this lane
  const int b = ((tid >> 4) << 1) | grp;   // batch index

  const float* wr = W_hh + j * 8;
  const float* wz = W_hh + (8 + j) * 8;
  const float* wn = W_hh + (16 + j) * 8;
  const float SN = -LOG2E, SP = 2.0f * LOG2E;
  // Packed f16 weight pairs, column-permuted to match (h[j^2m], h[j^2m+1]).
  const f16x2 wr0 = __builtin_amdgcn_cvt_pkrtz(SN * wr[j ^ 0], SN * wr[j ^ 1]);
  const f16x2 wr1 = __builtin_amdgcn_cvt_pkrtz(SN * wr[j ^ 2], SN * wr[j ^ 3]);
  const f16x2 wr2 = __builtin_amdgcn_cvt_pkrtz(SN * wr[j ^ 4], SN * wr[j ^ 5]);
  const f16x2 wr3 = __builtin_amdgcn_cvt_pkrtz(SN * wr[j ^ 6], SN * wr[j ^ 7]);
  const f16x2 wz0 = __builtin_amdgcn_cvt_pkrtz(SN * wz[j ^ 0], SN * wz[j ^ 1]);
  const f16x2 wz1 = __builtin_amdgcn_cvt_pkrtz(SN * wz[j ^ 2], SN * wz[j ^ 3]);
  const f16x2 wz2 = __builtin_amdgcn_cvt_pkrtz(SN * wz[j ^ 4], SN * wz[j ^ 5]);
  const f16x2 wz3 = __builtin_amdgcn_cvt_pkrtz(SN * wz[j ^ 6], SN * wz[j ^ 7]);
  const f16x2 wn0 = __builtin_amdgcn_cvt_pkrtz(SP * wn[j ^ 0], SP * wn[j ^ 1]);
  const f16x2 wn1 = __builtin_amdgcn_cvt_pkrtz(SP * wn[j ^ 2], SP * wn[j ^ 3]);
  const f16x2 wn2 = __builtin_amdgcn_cvt_pkrtz(SP * wn[j ^ 4], SP * wn[j ^ 5]);
  const f16x2 wn3 = __builtin_amdgcn_cvt_pkrtz(SP * wn[j ^ 6], SP * wn[j ^ 7]);

  const float c_r = SN * (b_ih[j] + b_hh[j]);
  const float c_z = SN * (b_ih[8 + j] + b_hh[8 + j]);
  const float c_n = SP * b_hh[16 + j];
  const float bi_n = SP * b_ih[16 + j];
  const float wi_r = SN * W_ih[j], wi_z = SN * W_ih[8 + j],
              wi_n = SP * W_ih[16 + j];
  const float wfc = W_fc[j];
  const float bfc8 = b_fc[0] * 0.125f;

  // Hoisted butterfly lane-select masks.
  const bool sel1 = (j & 1) != 0;
  const bool sel2 = (j & 2) != 0;
  const bool sel4 = (j & 4) != 0;

  const float* xp = x + (size_t)b * T_LEN;
  float* op = out + (size_t)b * T_LEN;

  float h = 0.0f;
  const float4* xq = reinterpret_cast<const float4*>(xp);
  float4 cA = xq[0], cB = xq[1], cC = xq[2], cD = xq[3];
  for (int t0 = 0; t0 < T_LEN; t0 += 16) {
    float4 nA4 = cA, nB4 = cB, nC4 = cC, nD4 = cD;
    if (t0 + 16 < T_LEN) {  // prefetch next 16 steps
      nA4 = xq[(t0 >> 2) + 4];
      nB4 = xq[(t0 >> 2) + 5];
      nC4 = xq[(t0 >> 2) + 6];
      nD4 = xq[(t0 >> 2) + 7];
    }
    float mA0, mA1, mA2, mA3, mA4, mA5, mA6, mA7;
    float mB0, mB1, mB2, mB3, mB4, mB5, mB6, mB7;
    STEP(cA.x, mA0);
    STEP(cA.y, mA1);
    STEP(cA.z, mA2);
    STEP(cA.w, mA3);
    STEP(cB.x, mA4);
    STEP(cB.y, mA5);
    STEP(cB.z, mA6);
    STEP(cB.w, mA7);
    // Butterfly A interleaves with steps 8-15 below (same basic block).
    BFLY_STORE(mA0, mA1, mA2, mA3, mA4, mA5, mA6, mA7, op[t0 + j]);
    STEP(cC.x, mB0);
    STEP(cC.y, mB1);
    STEP(cC.z, mB2);
    STEP(cC.w, mB3);
    STEP(cD.x, mB4);
    STEP(cD.y, mB5);
    STEP(cD.z, mB6);
    STEP(cD.w, mB7);
    BFLY_STORE(mB0, mB1, mB2, mB3, mB4, mB5, mB6, mB7, op[t0 + 8 + j]);
    cA = nA4;
    cB = nB4;
    cC = nC4;
    cD = nD4;
  }
}

extern "C" void kernel_launch(void* const* d_in, const int* in_sizes, int n_in,
                              void* d_out, int out_size, void* d_ws,
                              size_t ws_size, hipStream_t stream) {
  const float* x = (const float*)d_in[0];
  const float* W_ih = (const float*)d_in[1];
  const float* W_hh = (const float*)d_in[2];
  const float* b_ih = (const float*)d_in[3];
  const float* b_hh = (const float*)d_in[4];
  const float* W_fc = (const float*)d_in[5];
  const float* b_fc = (const float*)d_in[6];
  float* out = (float*)d_out;

  const int B = in_sizes[0] / T_LEN;  // 8192
  const int threads = B * 8;          // 8 lanes per batch
  gru_fused<<<threads / 256, 256, 0, stream>>>(x, W_ih, W_hh, b_ih, b_hh, W_fc,
                                               b_fc, out);
}

// Round 7
// 54.510 us; speedup vs baseline: 1.8204x; 1.0040x over previous
//
#include <hip/hip_runtime.h>

// Must match the element type of __builtin_amdgcn_cvt_pkrtz's return value.
typedef __fp16 f16x2 __attribute__((ext_vector_type(2)));

#define T_LEN 512
#define LOG2E 1.44269504f

// DPP cross-lane (VALU pipe). 8-lane group = quads {0,2} (or {1,3}) of a
// 16-lane DPP row: unit-index xor1/2/3 -> quad_perm, xor4 -> row_ror:8.
#define DPP_XOR1 0xB1   // quad_perm [1,0,3,2]
#define DPP_XOR2 0x4E   // quad_perm [2,3,0,1]
#define DPP_XOR8 0x128  // row_ror:8 (lane <- lane^8 within 16-row)

#define DPPI(v, ctrl) __builtin_amdgcn_update_dpp(0, (v), (ctrl), 0xF, 0xF, true)
#define DPPF(v, ctrl) __int_as_float(DPPI(__float_as_int(v), (ctrl)))
#define DPPH2(v, ctrl) \
  __builtin_bit_cast(f16x2, DPPI(__builtin_bit_cast(int, (v)), (ctrl)))

#define FDOT2(a, b, c) __builtin_amdgcn_fdot2((a), (b), (c), false)

// Per-step x-projection bases, hoisted to the 16-block head: a pool of 48
// independent FMAs the scheduler can use to fill trans-latency shadows.
#define BASE3(k, xi)                                            \
  const float bxr##k = __builtin_fmaf(xi, wi_r, c_r);           \
  const float bxz##k = __builtin_fmaf(xi, wi_z, c_z);           \
  const float bxn##k = __builtin_fmaf(xi, wi_n, bi_n);

// One GRU timestep, chain-minimized (exact algebra):
//   r  = 1/(1+er),  h' = [(ez+h)*ep + (h-ez)] / [(1+ez)*(1+ep)]
// (z-blend and tanh's divide folded into ONE rcp).
#define STEP(bxr, bxz, bxn, mdst)                                           \
  do {                                                                      \
    const f16x2 p01 = __builtin_amdgcn_cvt_pkrtz(h, DPPF(h, DPP_XOR1));     \
    const f16x2 p45 = DPPH2(p01, DPP_XOR8); /* (h[j^4],h[j^5]) */           \
    const f16x2 p23 = DPPH2(p01, DPP_XOR2); /* (h[j^2],h[j^3]) */           \
    const f16x2 p67 = DPPH2(p45, DPP_XOR2); /* (h[j^6],h[j^7]) */           \
    float rA = FDOT2(p01, wr0, bxr);                                        \
    rA = FDOT2(p23, wr1, rA);                                               \
    float rB = FDOT2(p45, wr2, 0.0f);                                       \
    rB = FDOT2(p67, wr3, rB);                                               \
    float zA = FDOT2(p01, wz0, bxz);                                        \
    zA = FDOT2(p23, wz1, zA);                                               \
    float zB = FDOT2(p45, wz2, 0.0f);                                       \
    zB = FDOT2(p67, wz3, zB);                                               \
    float nA = FDOT2(p01, wn0, c_n);                                        \
    nA = FDOT2(p23, wn1, nA);                                               \
    float nB = FDOT2(p45, wn2, 0.0f);                                       \
    nB = FDOT2(p67, wn3, nB);                                               \
    const float er = __builtin_amdgcn_exp2f(rA + rB);                       \
    const float ez = __builtin_amdgcn_exp2f(zA + zB);                       \
    const float r = __builtin_amdgcn_rcpf(1.0f + er); /* sigmoid(sr) */     \
    const float dz = 1.0f + ez;                                             \
    const float ezh = ez + h;  /* off-chain vs rcp/exp2 */                  \
    const float hez = h - ez;  /* off-chain */                              \
    const float pn = __builtin_fmaf(r, nA + nB, bxn);                       \
    const float ep = __builtin_amdgcn_exp2f(pn);                            \
    const float dp = 1.0f + ep;                                             \
    const float den = dz * dp;                                              \
    const float num = __builtin_fmaf(ezh, ep, hez); /* || with den */       \
    h = num * __builtin_amdgcn_rcpf(den);                                   \
    mdst = __builtin_fmaf(h, wfc, bfc8);                                    \
  } while (0)

// Shredded transpose-reduce: same op-DAG as before, but emitted in per-step
// fragments so each piece lands in the adjacent steps' trans shadows.
#define S1(s, m) float s = (m) + DPPF((m), DPP_XOR1);
#define P2(t, lo, hi)        \
  float t = sel1 ? (hi) : (lo); \
  t += DPPF(t, DPP_XOR2);
#define Q4(u, lo, hi)        \
  float u = sel2 ? (hi) : (lo); \
  u += DPPF(u, DPP_XOR8);
#define F8(lo, hi) (sel4 ? (hi) : (lo))

__global__ void __launch_bounds__(256, 1) gru_fused(
    const float* __restrict__ x, const float* __restrict__ W_ih,
    const float* __restrict__ W_hh, const float* __restrict__ b_ih,
    const float* __restrict__ b_hh, const float* __restrict__ W_fc,
    const float* __restrict__ b_fc, float* __restrict__ out) {
  const int tid = blockIdx.x * blockDim.x + threadIdx.x;
  // 8-lane group = quads {0,2} or {1,3} of a 16-lane row.
  const int pos = tid & 3;
  const int grp = (tid >> 2) & 1;
  const int hlf = (tid >> 3) & 1;
  const int j = pos | (hlf << 2);          // hidden unit owned by this lane
  const int b = ((tid >> 4) << 1) | grp;   // batch index

  const float* wr = W_hh + j * 8;
  const float* wz = W_hh + (8 + j) * 8;
  const float* wn = W_hh + (16 + j) * 8;
  const float SN = -LOG2E, SP = 2.0f * LOG2E;
  // Packed f16 weight pairs, column-permuted to match (h[j^2m], h[j^2m+1]).
  const f16x2 wr0 = __builtin_amdgcn_cvt_pkrtz(SN * wr[j ^ 0], SN * wr[j ^ 1]);
  const f16x2 wr1 = __builtin_amdgcn_cvt_pkrtz(SN * wr[j ^ 2], SN * wr[j ^ 3]);
  const f16x2 wr2 = __builtin_amdgcn_cvt_pkrtz(SN * wr[j ^ 4], SN * wr[j ^ 5]);
  const f16x2 wr3 = __builtin_amdgcn_cvt_pkrtz(SN * wr[j ^ 6], SN * wr[j ^ 7]);
  const f16x2 wz0 = __builtin_amdgcn_cvt_pkrtz(SN * wz[j ^ 0], SN * wz[j ^ 1]);
  const f16x2 wz1 = __builtin_amdgcn_cvt_pkrtz(SN * wz[j ^ 2], SN * wz[j ^ 3]);
  const f16x2 wz2 = __builtin_amdgcn_cvt_pkrtz(SN * wz[j ^ 4], SN * wz[j ^ 5]);
  const f16x2 wz3 = __builtin_amdgcn_cvt_pkrtz(SN * wz[j ^ 6], SN * wz[j ^ 7]);
  const f16x2 wn0 = __builtin_amdgcn_cvt_pkrtz(SP * wn[j ^ 0], SP * wn[j ^ 1]);
  const f16x2 wn1 = __builtin_amdgcn_cvt_pkrtz(SP * wn[j ^ 2], SP * wn[j ^ 3]);
  const f16x2 wn2 = __builtin_amdgcn_cvt_pkrtz(SP * wn[j ^ 4], SP * wn[j ^ 5]);
  const f16x2 wn3 = __builtin_amdgcn_cvt_pkrtz(SP * wn[j ^ 6], SP * wn[j ^ 7]);

  const float c_r = SN * (b_ih[j] + b_hh[j]);
  const float c_z = SN * (b_ih[8 + j] + b_hh[8 + j]);
  const float c_n = SP * b_hh[16 + j];
  const float bi_n = SP * b_ih[16 + j];
  const float wi_r = SN * W_ih[j], wi_z = SN * W_ih[8 + j],
              wi_n = SP * W_ih[16 + j];
  const float wfc = W_fc[j];
  const float bfc8 = b_fc[0] * 0.125f;

  // Hoisted butterfly lane-select masks.
  const bool sel1 = (j & 1) != 0;
  const bool sel2 = (j & 2) != 0;
  const bool sel4 = (j & 4) != 0;

  const float* xp = x + (size_t)b * T_LEN;
  float* op = out + (size_t)b * T_LEN;

  float h = 0.0f;
  const float4* xq = reinterpret_cast<const float4*>(xp);
  float4 cA = xq[0], cB = xq[1], cC = xq[2], cD = xq[3];
  for (int t0 = 0; t0 < T_LEN; t0 += 16) {
    float4 nA4 = cA, nB4 = cB, nC4 = cC, nD4 = cD;
    if (t0 + 16 < T_LEN) {  // prefetch next 16 steps
      nA4 = xq[(t0 >> 2) + 4];
      nB4 = xq[(t0 >> 2) + 5];
      nC4 = xq[(t0 >> 2) + 6];
      nD4 = xq[(t0 >> 2) + 7];
    }
    // Independent x-base pool (48 FMAs) — trans-shadow fillers.
    BASE3(0, cA.x) BASE3(1, cA.y) BASE3(2, cA.z) BASE3(3, cA.w)
    BASE3(4, cB.x) BASE3(5, cB.y) BASE3(6, cB.z) BASE3(7, cB.w)
    BASE3(8, cC.x) BASE3(9, cC.y) BASE3(10, cC.z) BASE3(11, cC.w)
    BASE3(12, cD.x) BASE3(13, cD.y) BASE3(14, cD.z) BASE3(15, cD.w)

    float mA0, mA1, mA2, mA3, mA4, mA5, mA6, mA7;
    float mB0, mB1, mB2, mB3, mB4, mB5, mB6, mB7;

    STEP(bxr0, bxz0, bxn0, mA0);  S1(sA0, mA0)
    STEP(bxr1, bxz1, bxn1, mA1);  S1(sA1, mA1)  P2(tA0, sA0, sA1)
    STEP(bxr2, bxz2, bxn2, mA2);  S1(sA2, mA2)
    STEP(bxr3, bxz3, bxn3, mA3);  S1(sA3, mA3)  P2(tA1, sA2, sA3)
    Q4(uA0, tA0, tA1)
    STEP(bxr4, bxz4, bxn4, mA4);  S1(sA4, mA4)
    STEP(bxr5, bxz5, bxn5, mA5);  S1(sA5, mA5)  P2(tA2, sA4, sA5)
    STEP(bxr6, bxz6, bxn6, mA6);  S1(sA6, mA6)
    STEP(bxr7, bxz7, bxn7, mA7);  S1(sA7, mA7)  P2(tA3, sA6, sA7)
    Q4(uA1, tA2, tA3)
    op[t0 + j] = F8(uA0, uA1);

    STEP(bxr8, bxz8, bxn8, mB0);   S1(sB0, mB0)
    STEP(bxr9, bxz9, bxn9, mB1);   S1(sB1, mB1)  P2(tB0, sB0, sB1)
    STEP(bxr10, bxz10, bxn10, mB2); S1(sB2, mB2)
    STEP(bxr11, bxz11, bxn11, mB3); S1(sB3, mB3)  P2(tB1, sB2, sB3)
    Q4(uB0, tB0, tB1)
    STEP(bxr12, bxz12, bxn12, mB4); S1(sB4, mB4)
    STEP(bxr13, bxz13, bxn13, mB5); S1(sB5, mB5)  P2(tB2, sB4, sB5)
    STEP(bxr14, bxz14, bxn14, mB6); S1(sB6, mB6)
    STEP(bxr15, bxz15, bxn15, mB7); S1(sB7, mB7)  P2(tB3, sB6, sB7)
    Q4(uB1, tB2, tB3)
    op[t0 + 8 + j] = F8(uB0, uB1);

    cA = nA4;
    cB = nB4;
    cC = nC4;
    cD = nD4;
  }
}

extern "C" void kernel_launch(void* const* d_in, const int* in_sizes, int n_in,
                              void* d_out, int out_size, void* d_ws,
                              size_t ws_size, hipStream_t stream) {
  const float* x = (const float*)d_in[0];
  const float* W_ih = (const float*)d_in[1];
  const float* W_hh = (const float*)d_in[2];
  const float* b_ih = (const float*)d_in[3];
  const float* b_hh = (const float*)d_in[4];
  const float* W_fc = (const float*)d_in[5];
  const float* b_fc = (const float*)d_in[6];
  float* out = (float*)d_out;

  const int B = in_sizes[0] / T_LEN;  // 8192
  const int threads = B * 8;          // 8 lanes per batch
  gru_fused<<<threads / 256, 256, 0, stream>>>(x, W_ih, W_hh, b_ih, b_hh, W_fc,
                                               b_fc, out);
}